// Round 4
// baseline (99.356 us; speedup 1.0000x reference)
//
#include <hip/hip_runtime.h>
#include <hip/hip_bf16.h>

#define C_DIM 256
#define W_DIM 4096
#define LDS_BYTES 78672

typedef unsigned short u16;
typedef short s16x8 __attribute__((ext_vector_type(8)));
typedef unsigned short u16x8 __attribute__((ext_vector_type(8)));
typedef unsigned short u16x4 __attribute__((ext_vector_type(4)));
typedef float f32x16 __attribute__((ext_vector_type(16)));

__device__ __forceinline__ u16 f2b(float f) {
  return __builtin_bit_cast(u16, __float2bfloat16(f));
}
__device__ __forceinline__ float b2f(u16 u) {
  return __builtin_bit_cast(float, ((unsigned)u) << 16);
}

// ---------------- prep kernel (unchanged) ----------------
// ws: [0,131072) M bf16 [256][256]; [131072,262144) Wv bf16;
//     [262144) u0[256] f32; [263168) u1[256] f32; [264192) c0 f32
__global__ __launch_bounds__(256) void prep_kernel(
    const float* __restrict__ Wq, const float* __restrict__ bq,
    const float* __restrict__ Wk, const float* __restrict__ bk,
    const float* __restrict__ Wv, char* __restrict__ ws) {
  u16* Mb   = (u16*)ws;
  u16* Wvb  = (u16*)(ws + 131072);
  float* u0 = (float*)(ws + 262144);
  float* u1 = (float*)(ws + 263168);
  float* c0p = (float*)(ws + 264192);
  int bid = blockIdx.x, t = threadIdx.x;
  if (bid < 256) {
    __shared__ float Wqs[256*17];
    __shared__ float Wks[256*17];
    int i0 = (bid >> 4) << 4, j0 = (bid & 15) << 4;
    for (int it = 0; it < 16; ++it) {
      int e = t + 256*it; int a = e >> 4, ii = e & 15;
      Wqs[a*17+ii] = Wq[a*256 + i0 + ii];
      Wks[a*17+ii] = Wk[a*256 + j0 + ii];
    }
    __syncthreads();
    int ii = t >> 4, jj = t & 15;
    float acc = 0.f;
    #pragma unroll 8
    for (int a = 0; a < 256; ++a) acc += Wqs[a*17+ii] * Wks[a*17+jj];
    Mb[(i0+ii)*256 + j0 + jj] = f2b(acc);
  } else if (bid == 256) {
    int j = t;
    float a0 = 0.f, a1 = 0.f;
    #pragma unroll 4
    for (int a = 0; a < 256; ++a) {
      a0 += bq[a] * Wk[a*256 + j];
      a1 += bk[a] * Wq[a*256 + j];
    }
    u0[j] = a0; u1[j] = a1;
    __shared__ float red[256];
    red[t] = bq[t] * bk[t];
    __syncthreads();
    if (t == 0) { float s = 0.f; for (int a = 0; a < 256; ++a) s += red[a]; *c0p = s; }
  } else {
    int base = ((bid - 257)*256 + t) * 4;
    const float4 v = *reinterpret_cast<const float4*>(Wv + base);
    ushort4 pk = make_ushort4(f2b(v.x), f2b(v.y), f2b(v.z), f2b(v.w));
    *reinterpret_cast<ushort4*>(Wvb + base) = pk;
  }
}

// ---------------- main fused kernel ----------------
// 1024 chunks of 64 output cols; grid 512 blocks x 2 chunks (same b per block).
// LDS: Xt[2][32][66][8] bf16 (67584) + PsA[2][8][66] f32 (4224)
//      + PsB[3][8][66] f32 (6336) + ABs[2][66] f32 (528) = 78672 B.
__global__ __launch_bounds__(512, 4) void main_kernel(
    const float* __restrict__ x, const char* __restrict__ ws,
    const float* __restrict__ bv, float* __restrict__ out) {
  const u16* Mb   = (const u16*)ws;
  const u16* Wvb  = (const u16*)(ws + 131072);
  const float* u0 = (const float*)(ws + 262144);
  const float* u1 = (const float*)(ws + 263168);
  const float c0  = *(const float*)(ws + 264192);

  extern __shared__ char lds[];
  u16* Xa    = (u16*)lds;               // 2 buffers, 16896 u16 each
  float* PsA = (float*)(lds + 67584);   // [2][8][66]
  float* PsB = (float*)(lds + 71808);   // [3][8][66]
  float* ABs = (float*)(lds + 78144);   // [2][66]

  const int bid = blockIdx.x;
  const int t = threadIdx.x;
  const int wv = t >> 6, l = t & 63;
  const int col = l & 31, half = l >> 5;

  const int gi0 = 2*bid;
  const int b   = gi0 >> 6;
  const int cw0 = gi0 & 63;
  const float* xb = x + (size_t)b * (C_DIM*W_DIM);
  float* outb = out + (size_t)b * (C_DIM*W_DIM);

  // ---- prologue: stage chunk gi0 into buffer 0 ----
  {
    const int w0 = cw0 * 64;
    int wg = w0 - 1 + l;
    bool ok = (wg >= 0);                      // upper bound always fine here
    const float* xp = xb + wg;
    #pragma unroll
    for (int r = 0; r < 4; ++r) {
      int kk = wv + 8*r;
      float v[8];
      #pragma unroll
      for (int e = 0; e < 8; ++e)
        v[e] = ok ? xp[(size_t)(kk*8+e) * W_DIM] : 0.f;
      union { u16 u[8]; u16x8 vv; } pk;
      #pragma unroll
      for (int e = 0; e < 8; ++e) pk.u[e] = f2b(v[e]);
      *reinterpret_cast<u16x8*>(Xa + (kk*66 + l)*8) = pk.vv;
    }
    if (t < 64) {                              // halo cols j=64,65
      int j = 64 + (t & 1), kk = t >> 1;
      int wge = w0 - 1 + j;
      bool oke = (wge < W_DIM);
      const float* xpe = xb + wge;
      union { u16 u[8]; u16x8 vv; } pk;
      #pragma unroll
      for (int e = 0; e < 8; ++e)
        pk.u[e] = oke ? f2b(xpe[(size_t)(kk*8+e)*W_DIM]) : (u16)0;
      *reinterpret_cast<u16x8*>(Xa + (kk*66 + j)*8) = pk.vv;
    }
  }
  __syncthreads();

  #pragma unroll
  for (int i = 0; i < 2; ++i) {
    const bool pf = (i == 0);
    u16* Xc = Xa + (i ? 16896 : 0);
    u16* Xn = Xa + (i ? 0 : 16896);
    const int cw = cw0 + i;
    const int w0 = cw * 64;
    const int w0n = w0 + 64;

    float pfv[8], pfe[8];
    const float* xpn = xb + (w0n - 1 + l);     // prefetched chunk: w always in-range for main cols

    // round 0: issue prefetch batch kk=wv (+ halo extras)
    if (pf) {
      #pragma unroll
      for (int e = 0; e < 8; ++e) pfv[e] = xpn[(size_t)(wv*8+e)*W_DIM];
      if (t < 64) {
        int j = 64 + (t&1), kk = t>>1;
        bool oke = (w0n - 1 + j) < W_DIM;
        const float* xpe = xb + (w0n - 1 + j);
        #pragma unroll
        for (int e = 0; e < 8; ++e) pfe[e] = oke ? xpe[(size_t)(kk*8+e)*W_DIM] : 0.f;
      }
    }

    // ---- GEMM1: G = M @ X, 3 n-tiles (cols 0-31, 32-63, 64-65+junk) ----
    f32x16 acc0, acc1, acc2;
    #pragma unroll
    for (int r = 0; r < 16; ++r) { acc0[r] = 0.f; acc1[r] = 0.f; acc2[r] = 0.f; }
    const u16* Arow = Mb + (32*wv + col)*256 + 8*half;
    #pragma unroll
    for (int kk = 0; kk < 8; ++kk) {
      s16x8 a = *reinterpret_cast<const s16x8*>(Arow + 16*kk);
      const u16* Bb = Xc + (2*kk + half)*66*8;
      s16x8 b0 = *reinterpret_cast<const s16x8*>(Bb + col*8);
      s16x8 b1 = *reinterpret_cast<const s16x8*>(Bb + (col+32)*8);
      s16x8 b2 = *reinterpret_cast<const s16x8*>(Bb + (col+64)*8);
      acc0 = __builtin_amdgcn_mfma_f32_32x32x16_bf16(a, b0, acc0, 0, 0, 0);
      acc1 = __builtin_amdgcn_mfma_f32_32x32x16_bf16(a, b1, acc1, 0, 0, 0);
      acc2 = __builtin_amdgcn_mfma_f32_32x32x16_bf16(a, b2, acc2, 0, 0, 0);
    }
    if (pf) {   // write batch0, issue batch1 (kk=wv+8)
      union { u16 u[8]; u16x8 vv; } pk;
      #pragma unroll
      for (int e = 0; e < 8; ++e) pk.u[e] = f2b(pfv[e]);
      *reinterpret_cast<u16x8*>(Xn + (wv*66 + l)*8) = pk.vv;
      #pragma unroll
      for (int e = 0; e < 8; ++e) pfv[e] = xpn[(size_t)((wv+8)*8+e)*W_DIM];
    }
    #pragma unroll
    for (int kk = 8; kk < 16; ++kk) {
      s16x8 a = *reinterpret_cast<const s16x8*>(Arow + 16*kk);
      const u16* Bb = Xc + (2*kk + half)*66*8;
      s16x8 b0 = *reinterpret_cast<const s16x8*>(Bb + col*8);
      s16x8 b1 = *reinterpret_cast<const s16x8*>(Bb + (col+32)*8);
      s16x8 b2 = *reinterpret_cast<const s16x8*>(Bb + (col+64)*8);
      acc0 = __builtin_amdgcn_mfma_f32_32x32x16_bf16(a, b0, acc0, 0, 0, 0);
      acc1 = __builtin_amdgcn_mfma_f32_32x32x16_bf16(a, b1, acc1, 0, 0, 0);
      acc2 = __builtin_amdgcn_mfma_f32_32x32x16_bf16(a, b2, acc2, 0, 0, 0);
    }
    if (pf) {   // write batch1, issue batch2 (kk=wv+16)
      union { u16 u[8]; u16x8 vv; } pk;
      #pragma unroll
      for (int e = 0; e < 8; ++e) pk.u[e] = f2b(pfv[e]);
      *reinterpret_cast<u16x8*>(Xn + ((wv+8)*66 + l)*8) = pk.vv;
      #pragma unroll
      for (int e = 0; e < 8; ++e) pfv[e] = xpn[(size_t)((wv+16)*8+e)*W_DIM];
    }

    // ---- P1.5: alpha/beta partials from bf16 Xt ----
    {
      float pa = 0.f, pb_ = 0.f;
      #pragma unroll
      for (int kg = 0; kg < 4; ++kg) {
        int kk = 4*wv + kg;
        u16x8 xv = *reinterpret_cast<const u16x8*>(Xc + (kk*66 + l)*8);
        #pragma unroll
        for (int e = 0; e < 8; ++e) {
          float xf = b2f(xv[e]);
          pa  += u0[kk*8+e] * xf;
          pb_ += u1[kk*8+e] * xf;
        }
      }
      PsA[wv*66 + l] = pa;
      PsA[528 + wv*66 + l] = pb_;
      if (l < 2) {                            // halo cols 64,65
        float ea = 0.f, eb = 0.f;
        #pragma unroll
        for (int kg = 0; kg < 4; ++kg) {
          int kk = 4*wv + kg;
          u16x8 xv = *reinterpret_cast<const u16x8*>(Xc + (kk*66 + 64 + l)*8);
          #pragma unroll
          for (int e = 0; e < 8; ++e) {
            float xf = b2f(xv[e]);
            ea += u0[kk*8+e] * xf;
            eb += u1[kk*8+e] * xf;
          }
        }
        PsA[wv*66 + 64 + l] = ea;
        PsA[528 + wv*66 + 64 + l] = eb;
      }
    }
    __syncthreads();   // barB

    if (pf) {   // write batch2, issue batch3 (kk=wv+24)
      union { u16 u[8]; u16x8 vv; } pk;
      #pragma unroll
      for (int e = 0; e < 8; ++e) pk.u[e] = f2b(pfv[e]);
      *reinterpret_cast<u16x8*>(Xn + ((wv+16)*66 + l)*8) = pk.vv;
      #pragma unroll
      for (int e = 0; e < 8; ++e) pfv[e] = xpn[(size_t)((wv+24)*8+e)*W_DIM];
    }
    // ABs reduce
    if (t < 132) {
      int which = (t >= 66) ? 1 : 0, jj = t - 66*which;
      float s = 0.f;
      #pragma unroll
      for (int g = 0; g < 8; ++g) s += PsA[which*528 + g*66 + jj];
      ABs[which*66 + jj] = s;
    }
    // ---- P2: score partials from acc regs ----
    {
      float t0s0=0.f,t0s1=0.f,t0s2=0.f,t1s0=0.f,t1s1=0.f,t1s2=0.f,t2s1=0.f,t2s2=0.f;
      const int e0 = 4*half;
      int jm0 = (col > 0) ? col-1 : 0;
      int jm2 = (63+col > 65) ? 65 : 63+col;
      int jc2 = (64+col > 65) ? 65 : 64+col;
      #pragma unroll
      for (int q = 0; q < 4; ++q) {
        const u16* base = Xc + (4*wv + q)*66*8 + e0;
        u16x4 xT0m = *reinterpret_cast<const u16x4*>(base + jm0*8);
        u16x4 xT0c = *reinterpret_cast<const u16x4*>(base + col*8);
        u16x4 xT0p = *reinterpret_cast<const u16x4*>(base + (col+1)*8);
        u16x4 xT1m = *reinterpret_cast<const u16x4*>(base + (col+31)*8);
        u16x4 xT1c = *reinterpret_cast<const u16x4*>(base + (col+32)*8);
        u16x4 xT1p = *reinterpret_cast<const u16x4*>(base + (col+33)*8);
        u16x4 xT2m = *reinterpret_cast<const u16x4*>(base + jm2*8);
        u16x4 xT2c = *reinterpret_cast<const u16x4*>(base + jc2*8);
        #pragma unroll
        for (int r4 = 0; r4 < 4; ++r4) {
          float g0 = acc0[4*q+r4], g1 = acc1[4*q+r4], g2 = acc2[4*q+r4];
          t0s1 += g0 * b2f(xT0c[r4]);
          t0s0 += g0 * b2f(xT0p[r4]);
          t0s2 += g0 * b2f(xT0m[r4]);
          t1s1 += g1 * b2f(xT1c[r4]);
          t1s0 += g1 * b2f(xT1p[r4]);
          t1s2 += g1 * b2f(xT1m[r4]);
          t2s1 += g2 * b2f(xT2c[r4]);
          t2s2 += g2 * b2f(xT2m[r4]);
        }
      }
      t0s0 += __shfl_xor(t0s0, 32); t0s1 += __shfl_xor(t0s1, 32);
      t0s2 += __shfl_xor(t0s2, 32); t1s0 += __shfl_xor(t1s0, 32);
      t1s1 += __shfl_xor(t1s1, 32); t1s2 += __shfl_xor(t1s2, 32);
      t2s1 += __shfl_xor(t2s1, 32); t2s2 += __shfl_xor(t2s2, 32);
      float* PBw = PsB + wv*66;
      if (half == 0) {
        PBw[0*528 + col+1]  = t0s0;
        PBw[1*528 + col]    = t0s1;
        if (col >= 1) PBw[2*528 + col-1] = t0s2;
        PBw[0*528 + col+33] = t1s0;
        PBw[1*528 + col+32] = t1s1;
        PBw[2*528 + col+31] = t1s2;
      } else if (col < 2) {
        PBw[1*528 + col+64] = t2s1;
        PBw[2*528 + col+63] = t2s2;
      }
    }
    __syncthreads();   // barC

    if (pf) {   // write batch3 + halo extras
      union { u16 u[8]; u16x8 vv; } pk;
      #pragma unroll
      for (int e = 0; e < 8; ++e) pk.u[e] = f2b(pfv[e]);
      *reinterpret_cast<u16x8*>(Xn + ((wv+24)*66 + l)*8) = pk.vv;
      if (t < 64) {
        int j = 64 + (t&1), kk = t>>1;
        union { u16 u[8]; u16x8 vv; } pke;
        #pragma unroll
        for (int e = 0; e < 8; ++e) pke.u[e] = f2b(pfe[e]);
        *reinterpret_cast<u16x8*>(Xn + (kk*66 + j)*8) = pke.vv;
      }
    }

    // ---- P3: softmax (output j=l+1, w=w0+l) + in-place mix ----
    {
      float d0 = 0.f, d1 = 0.f, d2 = 0.f;
      #pragma unroll
      for (int g = 0; g < 8; ++g) {
        d0 += PsB[0*528 + g*66 + l+1];
        d1 += PsB[1*528 + g*66 + l+1];
        d2 += PsB[2*528 + g*66 + l+1];
      }
      float am = ABs[l], ac = ABs[l+1], ap = ABs[l+2];
      float be = ABs[66 + l+1];
      float sc0 = (d0 + am + be + c0) * 0.0625f;
      float sc1 = (d1 + ac + be + c0) * 0.0625f;
      float sc2 = (d2 + ap + be + c0) * 0.0625f;
      int w = w0 + l;
      bool v0 = (w >= 1), v2 = (w + 1 < W_DIM);
      const float NEG = -1e30f;
      float m = fmaxf(v0 ? sc0 : NEG, fmaxf(sc1, v2 ? sc2 : NEG));
      float e0v = v0 ? __expf(sc0 - m) : 0.f;
      float e1v = __expf(sc1 - m);
      float e2v = v2 ? __expf(sc2 - m) : 0.f;
      float inv = 1.f / (e0v + e1v + e2v);
      float a0 = e0v*inv, a1 = e1v*inv, a2 = e2v*inv;
      #pragma unroll
      for (int kg = 0; kg < 4; ++kg) {
        int kk = 4*wv + kg;
        const u16* base = Xc + kk*66*8;
        u16x8 xm = *reinterpret_cast<const u16x8*>(base + l*8);
        u16x8 xc_ = *reinterpret_cast<const u16x8*>(base + (l+1)*8);
        u16x8 xp = *reinterpret_cast<const u16x8*>(base + (l+2)*8);
        union { u16 u[8]; u16x8 vv; } pk;
        #pragma unroll
        for (int e = 0; e < 8; ++e)
          pk.u[e] = f2b(a0*b2f(xm[e]) + a1*b2f(xc_[e]) + a2*b2f(xp[e]));
        *reinterpret_cast<u16x8*>(const_cast<u16*>(base) + (l+1)*8) = pk.vv;
      }
    }
    __syncthreads();   // barD

    // ---- P4: out = Wv @ Xmix + bv (dense aligned stores) ----
    {
      #pragma unroll
      for (int r = 0; r < 16; ++r) { acc0[r] = 0.f; acc1[r] = 0.f; }
      const u16* Arow2 = Wvb + (32*wv + col)*256 + 8*half;
      #pragma unroll
      for (int kk = 0; kk < 16; ++kk) {
        s16x8 a = *reinterpret_cast<const s16x8*>(Arow2 + 16*kk);
        const u16* Bb = Xc + (2*kk + half)*66*8;
        s16x8 b0 = *reinterpret_cast<const s16x8*>(Bb + (1+col)*8);
        s16x8 b1 = *reinterpret_cast<const s16x8*>(Bb + (33+col)*8);
        acc0 = __builtin_amdgcn_mfma_f32_32x32x16_bf16(a, b0, acc0, 0, 0, 0);
        acc1 = __builtin_amdgcn_mfma_f32_32x32x16_bf16(a, b1, acc1, 0, 0, 0);
      }
      float bvr[16];
      #pragma unroll
      for (int q = 0; q < 4; ++q) {
        float4 t4 = *reinterpret_cast<const float4*>(bv + 32*wv + 8*q + 4*half);
        bvr[4*q+0] = t4.x; bvr[4*q+1] = t4.y; bvr[4*q+2] = t4.z; bvr[4*q+3] = t4.w;
      }
      #pragma unroll
      for (int r = 0; r < 16; ++r) {
        int crow = 32*wv + (r&3) + 8*(r>>2) + 4*half;
        outb[(size_t)crow*W_DIM + w0 + col]      = acc0[r] + bvr[r];
        outb[(size_t)crow*W_DIM + w0 + 32 + col] = acc1[r] + bvr[r];
      }
    }
    __syncthreads();   // barE: protect Xc reads from next-iter staging writes
  }
}

extern "C" void kernel_launch(void* const* d_in, const int* in_sizes, int n_in,
                              void* d_out, int out_size, void* d_ws, size_t ws_size,
                              hipStream_t stream) {
  (void)in_sizes; (void)n_in; (void)out_size; (void)ws_size;
  const float* x  = (const float*)d_in[0];
  const float* Wq = (const float*)d_in[1];
  const float* bq = (const float*)d_in[2];
  const float* Wk = (const float*)d_in[3];
  const float* bk = (const float*)d_in[4];
  const float* Wv = (const float*)d_in[5];
  const float* bv = (const float*)d_in[6];
  float* out = (float*)d_out;
  char* ws = (char*)d_ws;   // needs 264196 B

  hipFuncSetAttribute((const void*)main_kernel,
                      hipFuncAttributeMaxDynamicSharedMemorySize, LDS_BYTES);
  prep_kernel<<<321, 256, 0, stream>>>(Wq, bq, Wk, bk, Wv, ws);
  main_kernel<<<512, 512, LDS_BYTES, stream>>>(x, ws, bv, out);
}